// Round 7
// baseline (202.661 us; speedup 1.0000x reference)
//
#include <hip/hip_runtime.h>
#include <math.h>

// Shapes: B=8, N=256, NID=64, V=GH=128, PHI=256, RHO=128
#define NB 8

// ---------------------------------------------------------------------------
// k_embed: H = relu(X@w1+b1)@w2+b2. 4 rows/block, grid 512, 512 threads.
// q = t&31 (f-quad of 128), u = t>>5 (K-slice of 16). Direct-from-L2 weights.
// Blocks 0..7 zero hsum/asum; block 8 zeroes the deepset done-counter.
// ---------------------------------------------------------------------------
__global__ __launch_bounds__(512, 4) void k_embed(const float* __restrict__ X,
        const float* __restrict__ w1, const float* __restrict__ b1,
        const float* __restrict__ w2, const float* __restrict__ b2,
        float* __restrict__ H, float* __restrict__ pools,
        unsigned* __restrict__ ctr) {
    const int r0 = blockIdx.x * 4;
    const int t = threadIdx.x, q = t & 31, u = t >> 5;
    __shared__ __align__(16) float part[8192];   // [16u][4r][128f]
    __shared__ __align__(16) float xq[256];      // [k][r]
    __shared__ __align__(16) float h1q[512];     // [k][r]
    if (blockIdx.x < 8) pools[blockIdx.x * 512 + t] = 0.f;
    if (blockIdx.x == 8 && t == 0) ctr[0] = 0u;
    if (t < 64) {
        float4 v;
        v.x = X[(size_t)(r0 + 0) * 64 + t];
        v.y = X[(size_t)(r0 + 1) * 64 + t];
        v.z = X[(size_t)(r0 + 2) * 64 + t];
        v.w = X[(size_t)(r0 + 3) * 64 + t];
        *(float4*)&xq[t * 4] = v;
    }
    __syncthreads();
    {   // L1: K=64, thread covers k in [u*4, u*4+4)
        float acc[16];
        #pragma unroll
        for (int i = 0; i < 16; ++i) acc[i] = 0.f;
        #pragma unroll
        for (int kk = 0; kk < 4; ++kk) {
            int k = u * 4 + kk;
            float4 w4 = *(const float4*)&w1[(size_t)k * 128 + q * 4];
            float wc[4] = {w4.x, w4.y, w4.z, w4.w};
            float4 x4 = *(const float4*)&xq[k * 4];
            float xr[4] = {x4.x, x4.y, x4.z, x4.w};
            #pragma unroll
            for (int r = 0; r < 4; ++r)
                #pragma unroll
                for (int c = 0; c < 4; ++c)
                    acc[r * 4 + c] = fmaf(xr[r], wc[c], acc[r * 4 + c]);
        }
        #pragma unroll
        for (int r = 0; r < 4; ++r)
            *(float4*)&part[u * 512 + r * 128 + q * 4] =
                make_float4(acc[r*4+0], acc[r*4+1], acc[r*4+2], acc[r*4+3]);
    }
    __syncthreads();
    {   // combine -> h1q: thread owns (r,f)
        int r = t >> 7, f = t & 127;
        float s = b1[f];
        #pragma unroll
        for (int uu = 0; uu < 16; ++uu) s += part[uu * 512 + r * 128 + f];
        h1q[f * 4 + r] = fmaxf(s, 0.f);
    }
    __syncthreads();
    {   // L2: K=128, thread covers k in [u*8, u*8+8)
        float a2[16];
        #pragma unroll
        for (int i = 0; i < 16; ++i) a2[i] = 0.f;
        #pragma unroll
        for (int kk = 0; kk < 8; ++kk) {
            int k = u * 8 + kk;
            float4 w4 = *(const float4*)&w2[(size_t)k * 128 + q * 4];
            float wc[4] = {w4.x, w4.y, w4.z, w4.w};
            float4 h4 = *(const float4*)&h1q[k * 4];
            float hr[4] = {h4.x, h4.y, h4.z, h4.w};
            #pragma unroll
            for (int r = 0; r < 4; ++r)
                #pragma unroll
                for (int c = 0; c < 4; ++c)
                    a2[r * 4 + c] = fmaf(hr[r], wc[c], a2[r * 4 + c]);
        }
        #pragma unroll
        for (int r = 0; r < 4; ++r)
            *(float4*)&part[u * 512 + r * 128 + q * 4] =
                make_float4(a2[r*4+0], a2[r*4+1], a2[r*4+2], a2[r*4+3]);
    }
    __syncthreads();
    {
        int r = t >> 7, f = t & 127;
        float s = b2[f];
        #pragma unroll
        for (int uu = 0; uu < 16; ++uu) s += part[uu * 512 + r * 128 + f];
        H[(size_t)(r0 + r) * 128 + f] = s;
    }
}

// ---------------------------------------------------------------------------
// k_gcn1: relation-mean aggregation + RGCN 3-matrix linear, fused.
// 512 threads; block = (b, 4 targets). Phase A i-slices of 16 per thread;
// two-pass rel combine keeps part at 32 KB. Weights direct from L2.
// ---------------------------------------------------------------------------
__global__ __launch_bounds__(512, 4) void k_gcn1(
        const float* __restrict__ A, const float* __restrict__ H,
        const float* __restrict__ Wrel, const float* __restrict__ Wroot,
        const float* __restrict__ bias, float* __restrict__ H2) {
    const int b  = blockIdx.x >> 6;
    const int j0 = (blockIdx.x & 63) * 4;
    const int t = threadIdx.x, q = t & 31, u = t >> 5;
    __shared__ __align__(16) float maskM[2048];  // [256][8]
    __shared__ __align__(16) float part[8192];   // [16u][4r][128f]
    __shared__ __align__(16) float pb[1536];     // [k][h4|m0_4|m1_4]
    __shared__ float cntp[256];
    __shared__ float cnt[8];
    const float* Ab = A + (size_t)b * 65536;
    const float* Hb = H + (size_t)b * 32768;
    const float* W0 = Wrel;
    const float* W1 = Wrel + 16384;

    if (t < 256) {   // masks: thread t owns row i=t
        float4 a = *(const float4*)(Ab + (size_t)t * 256 + j0);
        float4 m0, m1;
        m0.x = (a.x < 0.f) ? 1.f : 0.f; m1.x = (a.x > 0.f) ? 1.f : 0.f;
        m0.y = (a.y < 0.f) ? 1.f : 0.f; m1.y = (a.y > 0.f) ? 1.f : 0.f;
        m0.z = (a.z < 0.f) ? 1.f : 0.f; m1.z = (a.z > 0.f) ? 1.f : 0.f;
        m0.w = (a.w < 0.f) ? 1.f : 0.f; m1.w = (a.w > 0.f) ? 1.f : 0.f;
        *(float4*)&maskM[t * 8]     = m0;
        *(float4*)&maskM[t * 8 + 4] = m1;
    }
    __syncthreads();
    if (t < 256) {   // count partials: 32 chunks x 8 slots
        int chunk = t >> 3, slot = t & 7;
        float c = 0.f;
        #pragma unroll
        for (int qq = 0; qq < 8; ++qq) c += maskM[(chunk * 8 + qq) * 8 + slot];
        cntp[slot * 32 + chunk] = c;
    }
    // phase A: thread sweeps i in [u*16, u*16+16), H direct from L2
    float acc0[16], acc1[16];
    #pragma unroll
    for (int i = 0; i < 16; ++i) { acc0[i] = 0.f; acc1[i] = 0.f; }
    #pragma unroll 8
    for (int ii = 0; ii < 16; ++ii) {
        int i = u * 16 + ii;
        float4 h4 = *(const float4*)&Hb[(size_t)i * 128 + q * 4];
        float hc[4] = {h4.x, h4.y, h4.z, h4.w};
        float4 m0 = *(const float4*)&maskM[i * 8];
        float4 m1 = *(const float4*)&maskM[i * 8 + 4];
        float mr0[4] = {m0.x, m0.y, m0.z, m0.w};
        float mr1[4] = {m1.x, m1.y, m1.z, m1.w};
        #pragma unroll
        for (int r = 0; r < 4; ++r)
            #pragma unroll
            for (int c = 0; c < 4; ++c) {
                acc0[r * 4 + c] = fmaf(mr0[r], hc[c], acc0[r * 4 + c]);
                acc1[r * 4 + c] = fmaf(mr1[r], hc[c], acc1[r * 4 + c]);
            }
    }
    // pass 1: rel0
    #pragma unroll
    for (int r = 0; r < 4; ++r)
        *(float4*)&part[u * 512 + r * 128 + q * 4] =
            make_float4(acc0[r*4+0], acc0[r*4+1], acc0[r*4+2], acc0[r*4+3]);
    if (t < 8) {
        float s = 0.f;
        #pragma unroll
        for (int c = 0; c < 32; ++c) s += cntp[t * 32 + c];
        cnt[t] = s;
    }
    __syncthreads();
    {
        int r = t >> 7, f = t & 127;
        float s = 0.f;
        #pragma unroll
        for (int uu = 0; uu < 16; ++uu) s += part[uu * 512 + r * 128 + f];
        pb[f * 12 + 4 + r] = s * (1.f / fmaxf(cnt[r], 1.f));
    }
    __syncthreads();
    // pass 2: rel1 + root rows
    #pragma unroll
    for (int r = 0; r < 4; ++r)
        *(float4*)&part[u * 512 + r * 128 + q * 4] =
            make_float4(acc1[r*4+0], acc1[r*4+1], acc1[r*4+2], acc1[r*4+3]);
    __syncthreads();
    {
        int r = t >> 7, f = t & 127;
        float s = 0.f;
        #pragma unroll
        for (int uu = 0; uu < 16; ++uu) s += part[uu * 512 + r * 128 + f];
        pb[f * 12 + 8 + r] = s * (1.f / fmaxf(cnt[4 + r], 1.f));
    }
    if (t < 128) {  // root rows -> pb
        int r = t >> 5, fq = t & 31;
        float4 g4 = *(const float4*)(Hb + (size_t)(j0 + r) * 128 + fq * 4);
        pb[(fq * 4 + 0) * 12 + r] = g4.x;
        pb[(fq * 4 + 1) * 12 + r] = g4.y;
        pb[(fq * 4 + 2) * 12 + r] = g4.z;
        pb[(fq * 4 + 3) * 12 + r] = g4.w;
    }
    __syncthreads();
    // phase B: K=128, thread covers k in [u*8, u*8+8), weights direct
    float bcc[16];
    #pragma unroll
    for (int i = 0; i < 16; ++i) bcc[i] = 0.f;
    #pragma unroll 4
    for (int kk = 0; kk < 8; ++kk) {
        int k = u * 8 + kk;
        float4 wr = *(const float4*)&Wroot[(size_t)k * 128 + q * 4];
        float4 wa = *(const float4*)&W0[(size_t)k * 128 + q * 4];
        float4 wb = *(const float4*)&W1[(size_t)k * 128 + q * 4];
        float wrc[4] = {wr.x, wr.y, wr.z, wr.w};
        float wac[4] = {wa.x, wa.y, wa.z, wa.w};
        float wbc[4] = {wb.x, wb.y, wb.z, wb.w};
        float4 hv = *(const float4*)&pb[k * 12];
        float4 q0 = *(const float4*)&pb[k * 12 + 4];
        float4 q1 = *(const float4*)&pb[k * 12 + 8];
        float hr[4] = {hv.x, hv.y, hv.z, hv.w};
        float m0r[4] = {q0.x, q0.y, q0.z, q0.w};
        float m1r[4] = {q1.x, q1.y, q1.z, q1.w};
        #pragma unroll
        for (int r = 0; r < 4; ++r)
            #pragma unroll
            for (int c = 0; c < 4; ++c) {
                float v = bcc[r * 4 + c];
                v = fmaf(hr[r], wrc[c], v);
                v = fmaf(m0r[r], wac[c], v);
                v = fmaf(m1r[r], wbc[c], v);
                bcc[r * 4 + c] = v;
            }
    }
    #pragma unroll
    for (int r = 0; r < 4; ++r)
        *(float4*)&part[u * 512 + r * 128 + q * 4] =
            make_float4(bcc[r*4+0], bcc[r*4+1], bcc[r*4+2], bcc[r*4+3]);
    __syncthreads();
    {
        int r = t >> 7, f = t & 127;
        float s = bias[f];
        #pragma unroll
        for (int uu = 0; uu < 16; ++uu) s += part[uu * 512 + r * 128 + f];
        H2[(size_t)(b * 256 + j0 + r) * 128 + f] = s;
    }
}

// ---------------------------------------------------------------------------
// k_gcn2: |A|-aggregation + LayerNorm + 2-layer MLP + H-update, fused.
// 512 threads; H2/weights direct from L2; LDS only for reductions.
// ---------------------------------------------------------------------------
__global__ __launch_bounds__(512, 4) void k_gcn2(
        const float* __restrict__ A, const float* __restrict__ H2,
        const float* __restrict__ g, const float* __restrict__ bta,
        const float* __restrict__ law, const float* __restrict__ lab,
        const float* __restrict__ lbw, const float* __restrict__ lbb,
        float* __restrict__ H) {
    const int b  = blockIdx.x >> 6;
    const int i0 = (blockIdx.x & 63) * 4;
    const int t = threadIdx.x, q = t & 31, u = t >> 5;
    __shared__ __align__(16) float part[8192];   // [16u][4r][128f]
    __shared__ __align__(16) float absA[1024];   // [256][4]
    __shared__ __align__(16) float xq[512];      // [k][r]
    __shared__ __align__(16) float uq[512];      // [k][r]
    __shared__ float red[16];
    __shared__ float mi[8];
    const float* Ab  = A + (size_t)b * 65536;
    const float* H2b = H2 + (size_t)b * 32768;

    if (t < 256) {
        float4 av;
        av.x = fabsf(Ab[(size_t)(i0 + 0) * 256 + t]);
        av.y = fabsf(Ab[(size_t)(i0 + 1) * 256 + t]);
        av.z = fabsf(Ab[(size_t)(i0 + 2) * 256 + t]);
        av.w = fabsf(Ab[(size_t)(i0 + 3) * 256 + t]);
        *(float4*)&absA[t * 4] = av;
    }
    __syncthreads();
    // phase A: thread sweeps j in [u*16, u*16+16)
    float acc[16];
    #pragma unroll
    for (int i = 0; i < 16; ++i) acc[i] = 0.f;
    #pragma unroll 8
    for (int jj = 0; jj < 16; ++jj) {
        int j = u * 16 + jj;
        float4 h4 = *(const float4*)&H2b[(size_t)j * 128 + q * 4];
        float hc[4] = {h4.x, h4.y, h4.z, h4.w};
        float4 a4 = *(const float4*)&absA[j * 4];
        float ar[4] = {a4.x, a4.y, a4.z, a4.w};
        #pragma unroll
        for (int r = 0; r < 4; ++r)
            #pragma unroll
            for (int c = 0; c < 4; ++c)
                acc[r * 4 + c] = fmaf(ar[r], hc[c], acc[r * 4 + c]);
    }
    #pragma unroll
    for (int r = 0; r < 4; ++r)
        *(float4*)&part[u * 512 + r * 128 + q * 4] =
            make_float4(acc[r*4+0], acc[r*4+1], acc[r*4+2], acc[r*4+3]);
    __syncthreads();
    // combine + LN: thread owns (r,f); row r = waves 2r,2r+1
    const int rr = t >> 7, ff = t & 127;
    float x;
    {
        float s = 0.f;
        #pragma unroll
        for (int uu = 0; uu < 16; ++uu) s += part[uu * 512 + rr * 128 + ff];
        x = s;
        float s2 = x * x;
        float sw = x;
        #pragma unroll
        for (int o = 32; o > 0; o >>= 1) {
            sw += __shfl_down(sw, o, 64);
            s2 += __shfl_down(s2, o, 64);
        }
        int w = (t >> 6) & 1;
        if ((t & 63) == 0) {
            red[(rr * 2 + w) * 2]     = sw;
            red[(rr * 2 + w) * 2 + 1] = s2;
        }
    }
    __syncthreads();
    if (t < 4) {
        float s  = red[t * 4]     + red[t * 4 + 2];
        float s2 = red[t * 4 + 1] + red[t * 4 + 3];
        float m = s * (1.f / 128.f);
        float v = s2 * (1.f / 128.f) - m * m;
        mi[t * 2] = m;
        mi[t * 2 + 1] = rsqrtf(v + 1e-5f);
    }
    __syncthreads();
    xq[ff * 4 + rr] = fmaxf((x - mi[rr * 2]) * mi[rr * 2 + 1] * g[ff] + bta[ff], 0.f);
    __syncthreads();
    // MLP layer A: K=128, thread covers k in [u*8, u*8+8)
    float u1[16];
    #pragma unroll
    for (int i = 0; i < 16; ++i) u1[i] = 0.f;
    #pragma unroll
    for (int kk = 0; kk < 8; ++kk) {
        int k = u * 8 + kk;
        float4 w4 = *(const float4*)&law[(size_t)k * 128 + q * 4];
        float wc[4] = {w4.x, w4.y, w4.z, w4.w};
        float4 x4 = *(const float4*)&xq[k * 4];
        float xr[4] = {x4.x, x4.y, x4.z, x4.w};
        #pragma unroll
        for (int r = 0; r < 4; ++r)
            #pragma unroll
            for (int c = 0; c < 4; ++c)
                u1[r * 4 + c] = fmaf(xr[r], wc[c], u1[r * 4 + c]);
    }
    #pragma unroll
    for (int r = 0; r < 4; ++r)
        *(float4*)&part[u * 512 + r * 128 + q * 4] =
            make_float4(u1[r*4+0], u1[r*4+1], u1[r*4+2], u1[r*4+3]);
    __syncthreads();
    {
        float s = lab[ff];
        #pragma unroll
        for (int uu = 0; uu < 16; ++uu) s += part[uu * 512 + rr * 128 + ff];
        uq[ff * 4 + rr] = fmaxf(s, 0.f);
    }
    __syncthreads();
    // MLP layer B: K=128
    float u2[16];
    #pragma unroll
    for (int i = 0; i < 16; ++i) u2[i] = 0.f;
    #pragma unroll
    for (int kk = 0; kk < 8; ++kk) {
        int k = u * 8 + kk;
        float4 w4 = *(const float4*)&lbw[(size_t)k * 128 + q * 4];
        float wc[4] = {w4.x, w4.y, w4.z, w4.w};
        float4 x4 = *(const float4*)&uq[k * 4];
        float xr[4] = {x4.x, x4.y, x4.z, x4.w};
        #pragma unroll
        for (int r = 0; r < 4; ++r)
            #pragma unroll
            for (int c = 0; c < 4; ++c)
                u2[r * 4 + c] = fmaf(xr[r], wc[c], u2[r * 4 + c]);
    }
    #pragma unroll
    for (int r = 0; r < 4; ++r)
        *(float4*)&part[u * 512 + r * 128 + q * 4] =
            make_float4(u2[r*4+0], u2[r*4+1], u2[r*4+2], u2[r*4+3]);
    __syncthreads();
    {
        float s = lbb[ff];
        #pragma unroll
        for (int uu = 0; uu < 16; ++uu) s += part[uu * 512 + rr * 128 + ff];
        size_t idx = (size_t)(b * 256 + i0 + rr) * 128 + ff;
        H[idx] = s + H[idx];
    }
}

// ---------------------------------------------------------------------------
// k_deepset: phi (128->256->256 relu) + masked pooling. 4 rows/block,
// grid 512, 512 threads. q = t&63 (f-quad of 256), u = t>>6 (K-slice of 8).
// Weights direct from L2. LAST block (done-counter) computes rho + output:
// hsum/asum read via agent-scope atomic loads (coherent vs other XCDs).
// ---------------------------------------------------------------------------
__global__ __launch_bounds__(512, 4) void k_deepset(
        const float* __restrict__ H, const float* __restrict__ hm,
        const float* __restrict__ w1, const float* __restrict__ b1,
        const float* __restrict__ w2, const float* __restrict__ b2,
        float* __restrict__ hsum, float* __restrict__ asum,
        const float* __restrict__ qw1, const float* __restrict__ qb1,
        const float* __restrict__ qw2, float* __restrict__ out,
        unsigned* __restrict__ ctr) {
    const int r0 = blockIdx.x * 4;
    const int b  = blockIdx.x >> 6;
    const int t  = threadIdx.x, q = t & 63, u = t >> 6;
    __shared__ __align__(16) float part[8192];   // [8u][4r][256f]; reused for rho
    __shared__ __align__(16) float ph2[1024];    // [r][256]
    __shared__ __align__(16) float hraw[512];    // [r][128]
    __shared__ float hmv[4];
    __shared__ float pr[16];
    __shared__ int lastFlag;
    if (t < 128) {
        float4 g4 = *(const float4*)&H[(size_t)r0 * 128 + t * 4];
        *(float4*)&hraw[t * 4] = g4;
    }
    if (t < 4) hmv[t] = hm[r0 + t];
    __syncthreads();
    // L1: K=128, thread covers k in [u*16, u*16+16)
    float acc[16];
    #pragma unroll
    for (int i = 0; i < 16; ++i) acc[i] = 0.f;
    #pragma unroll 8
    for (int kk = 0; kk < 16; ++kk) {
        int k = u * 16 + kk;
        float4 w4 = *(const float4*)&w1[(size_t)k * 256 + q * 4];
        float wc[4] = {w4.x, w4.y, w4.z, w4.w};
        float hr[4];
        #pragma unroll
        for (int r = 0; r < 4; ++r) hr[r] = hraw[r * 128 + k];
        #pragma unroll
        for (int r = 0; r < 4; ++r)
            #pragma unroll
            for (int c = 0; c < 4; ++c)
                acc[r * 4 + c] = fmaf(hr[r], wc[c], acc[r * 4 + c]);
    }
    #pragma unroll
    for (int r = 0; r < 4; ++r)
        *(float4*)&part[u * 1024 + r * 256 + q * 4] =
            make_float4(acc[r*4+0], acc[r*4+1], acc[r*4+2], acc[r*4+3]);
    __syncthreads();
    {   // combine L1 -> ph2 (relu): 1024 outputs, 2 per thread
        #pragma unroll
        for (int e = 0; e < 2; ++e) {
            int idx = e * 512 + t;
            int r = idx >> 8, f = idx & 255;
            float s = b1[f];
            #pragma unroll
            for (int uu = 0; uu < 8; ++uu) s += part[uu * 1024 + r * 256 + f];
            ph2[r * 256 + f] = fmaxf(s, 0.f);
        }
    }
    __syncthreads();
    // L2: K=256, thread covers k in [u*32, u*32+32)
    float a2[16];
    #pragma unroll
    for (int i = 0; i < 16; ++i) a2[i] = 0.f;
    #pragma unroll 8
    for (int kk = 0; kk < 32; ++kk) {
        int k = u * 32 + kk;
        float4 w4 = *(const float4*)&w2[(size_t)k * 256 + q * 4];
        float wc[4] = {w4.x, w4.y, w4.z, w4.w};
        float pv[4];
        #pragma unroll
        for (int r = 0; r < 4; ++r) pv[r] = ph2[r * 256 + k];
        #pragma unroll
        for (int r = 0; r < 4; ++r)
            #pragma unroll
            for (int c = 0; c < 4; ++c)
                a2[r * 4 + c] = fmaf(pv[r], wc[c], a2[r * 4 + c]);
    }
    __syncthreads();
    #pragma unroll
    for (int r = 0; r < 4; ++r)
        *(float4*)&part[u * 1024 + r * 256 + q * 4] =
            make_float4(a2[r*4+0], a2[r*4+1], a2[r*4+2], a2[r*4+3]);
    __syncthreads();
    if (t < 256) {   // final combine + relu + masked pool (f = t)
        float bb = b2[t];
        float hp = 0.f, sp = 0.f;
        #pragma unroll
        for (int r = 0; r < 4; ++r) {
            float s = bb;
            #pragma unroll
            for (int uu = 0; uu < 8; ++uu) s += part[uu * 1024 + r * 256 + t];
            float p = fmaxf(s, 0.f);
            sp += p;
            hp = fmaf(p, hmv[r], hp);
        }
        atomicAdd(&hsum[b * 256 + t], hp);
        atomicAdd(&asum[b * 256 + t], sp - hp);
    }
    // ---- last-block-done: compute rho ----
    __syncthreads();   // drains vmcnt -> this block's atomics are L2-visible
    if (t == 0) {
        unsigned v = __hip_atomic_fetch_add(ctr, 1u, __ATOMIC_ACQ_REL,
                                            __HIP_MEMORY_SCOPE_AGENT);
        lastFlag = (v == 511u) ? 1 : 0;
    }
    __syncthreads();
    if (!lastFlag) return;
    // coherent load of all pooled sums into LDS (hsum||asum contiguous, 4096)
    #pragma unroll
    for (int e = 0; e < 8; ++e) {
        int idx = e * 512 + t;
        part[idx] = __hip_atomic_load(&hsum[idx], __ATOMIC_RELAXED,
                                      __HIP_MEMORY_SCOPE_AGENT);
    }
    __syncthreads();
    {   // vec = b*2+side (16 vecs x 32 lanes); thread owns j in [qr*4, qr*4+4)
        int vec = t >> 5, qr = t & 31;
        int bb2 = vec >> 1, side = vec & 1;
        const float* s = &part[side * 2048 + bb2 * 256];
        float a0 = 0.f, a1 = 0.f, a2r = 0.f, a3 = 0.f;
        #pragma unroll 8
        for (int k = 0; k < 256; ++k) {
            float4 w4 = *(const float4*)&qw1[(size_t)k * 128 + qr * 4];
            float sk = s[k];
            a0  = fmaf(sk, w4.x, a0);
            a1  = fmaf(sk, w4.y, a1);
            a2r = fmaf(sk, w4.z, a2r);
            a3  = fmaf(sk, w4.w, a3);
        }
        float4 bb = *(const float4*)&qb1[qr * 4];
        float4 w2q = *(const float4*)&qw2[qr * 4];
        float p = fmaxf(a0 + bb.x, 0.f) * w2q.x
                + fmaxf(a1 + bb.y, 0.f) * w2q.y
                + fmaxf(a2r + bb.z, 0.f) * w2q.z
                + fmaxf(a3 + bb.w, 0.f) * w2q.w;
        #pragma unroll
        for (int o = 16; o > 0; o >>= 1) p += __shfl_down(p, o, 32);
        if (qr == 0) pr[vec] = p;
    }
    __syncthreads();
    if (t < 8) out[t] = 0.5f + 0.5f * tanhf(pr[t * 2] - pr[t * 2 + 1]);
}

// ---------------------------------------------------------------------------
extern "C" void kernel_launch(void* const* d_in, const int* in_sizes, int n_in,
                              void* d_out, int out_size, void* d_ws, size_t ws_size,
                              hipStream_t stream) {
    const float* A         = (const float*)d_in[0];
    const float* X         = (const float*)d_in[1];
    const float* home_mask = (const float*)d_in[2];
    const float* emb1_w    = (const float*)d_in[3];
    const float* emb1_b    = (const float*)d_in[4];
    const float* emb2_w    = (const float*)d_in[5];
    const float* emb2_b    = (const float*)d_in[6];
    const float* rgcn_w[2]    = { (const float*)d_in[7],  (const float*)d_in[14] };
    const float* rgcn_root[2] = { (const float*)d_in[8],  (const float*)d_in[15] };
    const float* rgcn_bias[2] = { (const float*)d_in[9],  (const float*)d_in[16] };
    const float* lina_w[2]    = { (const float*)d_in[10], (const float*)d_in[17] };
    const float* lina_b[2]    = { (const float*)d_in[11], (const float*)d_in[18] };
    const float* linb_w[2]    = { (const float*)d_in[12], (const float*)d_in[19] };
    const float* linb_b[2]    = { (const float*)d_in[13], (const float*)d_in[20] };
    const float* norm_g  = (const float*)d_in[21];
    const float* norm_b  = (const float*)d_in[22];
    const float* phi_w1  = (const float*)d_in[23];
    const float* phi_b1  = (const float*)d_in[24];
    const float* phi_w2  = (const float*)d_in[25];
    const float* phi_b2  = (const float*)d_in[26];
    const float* rho_w1  = (const float*)d_in[27];
    const float* rho_b1  = (const float*)d_in[28];
    const float* rho_w2  = (const float*)d_in[29];
    const float* rho_b2  = (const float*)d_in[30];
    float* out = (float*)d_out;

    float* ws   = (float*)d_ws;
    float* H    = ws;               // 262144
    float* H2   = ws + 262144;      // 262144
    float* hsum = ws + 524288;      // 2048
    float* asum = ws + 526336;      // 2048 (contiguous with hsum)
    unsigned* ctr = (unsigned*)(ws + 528384);

    k_embed<<<512, 512, 0, stream>>>(X, emb1_w, emb1_b, emb2_w, emb2_b, H,
                                     hsum, ctr);

    for (int it = 0; it < 2; ++it) {
        k_gcn1<<<512, 512, 0, stream>>>(A, H, rgcn_w[it], rgcn_root[it],
                                        rgcn_bias[it], H2);
        k_gcn2<<<512, 512, 0, stream>>>(A, H2, norm_g, norm_b,
                                        lina_w[it], lina_b[it],
                                        linb_w[it], linb_b[it], H);
    }

    k_deepset<<<512, 512, 0, stream>>>(H, home_mask, phi_w1, phi_b1,
                                       phi_w2, phi_b2, hsum, asum,
                                       rho_w1, rho_b1, rho_w2, out, ctr);
}

// Round 8
// 182.293 us; speedup vs baseline: 1.1117x; 1.1117x over previous
//
#include <hip/hip_runtime.h>
#include <math.h>

// Shapes: B=8, N=256, NID=64, V=GH=128, PHI=256, RHO=128
#define NB 8

#define KEEP(x) asm volatile("" :: "v"(x))

// ---------------------------------------------------------------------------
// k_embed: H = relu(X@w1+b1)@w2+b2. 4 rows/block, grid 512, 512 threads.
// q = t&31 (f-quad of 128), u = t>>5 (K-slice of 16). Direct-from-L2 weights.
// w2 lines prefetched during L1 to overlap cold HBM fetch.
// ---------------------------------------------------------------------------
__global__ __launch_bounds__(512, 4) void k_embed(const float* __restrict__ X,
        const float* __restrict__ w1, const float* __restrict__ b1,
        const float* __restrict__ w2, const float* __restrict__ b2,
        float* __restrict__ H, float* __restrict__ pools) {
    const int r0 = blockIdx.x * 4;
    const int t = threadIdx.x, q = t & 31, u = t >> 5;
    __shared__ __align__(16) float part[8192];   // [16u][4r][128f]
    __shared__ __align__(16) float xq[256];      // [k][r]
    __shared__ __align__(16) float h1q[512];     // [k][r]
    if (blockIdx.x < 8) pools[blockIdx.x * 512 + t] = 0.f;
    {   // prefetch future w2 lines (k = u*8 .. +8, stride 2) -> warm L2/L1
        float pf = 0.f;
        #pragma unroll
        for (int kk = 0; kk < 8; kk += 2)
            pf += w2[(size_t)(u * 8 + kk) * 128 + q * 4];
        KEEP(pf);
    }
    if (t < 64) {
        float4 v;
        v.x = X[(size_t)(r0 + 0) * 64 + t];
        v.y = X[(size_t)(r0 + 1) * 64 + t];
        v.z = X[(size_t)(r0 + 2) * 64 + t];
        v.w = X[(size_t)(r0 + 3) * 64 + t];
        *(float4*)&xq[t * 4] = v;
    }
    __syncthreads();
    {   // L1: K=64, thread covers k in [u*4, u*4+4)
        float acc[16];
        #pragma unroll
        for (int i = 0; i < 16; ++i) acc[i] = 0.f;
        #pragma unroll
        for (int kk = 0; kk < 4; ++kk) {
            int k = u * 4 + kk;
            float4 w4 = *(const float4*)&w1[(size_t)k * 128 + q * 4];
            float wc[4] = {w4.x, w4.y, w4.z, w4.w};
            float4 x4 = *(const float4*)&xq[k * 4];
            float xr[4] = {x4.x, x4.y, x4.z, x4.w};
            #pragma unroll
            for (int r = 0; r < 4; ++r)
                #pragma unroll
                for (int c = 0; c < 4; ++c)
                    acc[r * 4 + c] = fmaf(xr[r], wc[c], acc[r * 4 + c]);
        }
        #pragma unroll
        for (int r = 0; r < 4; ++r)
            *(float4*)&part[u * 512 + r * 128 + q * 4] =
                make_float4(acc[r*4+0], acc[r*4+1], acc[r*4+2], acc[r*4+3]);
    }
    __syncthreads();
    {   // combine -> h1q: thread owns (r,f)
        int r = t >> 7, f = t & 127;
        float s = b1[f];
        #pragma unroll
        for (int uu = 0; uu < 16; ++uu) s += part[uu * 512 + r * 128 + f];
        h1q[f * 4 + r] = fmaxf(s, 0.f);
    }
    __syncthreads();
    {   // L2: K=128, thread covers k in [u*8, u*8+8)
        float a2[16];
        #pragma unroll
        for (int i = 0; i < 16; ++i) a2[i] = 0.f;
        #pragma unroll
        for (int kk = 0; kk < 8; ++kk) {
            int k = u * 8 + kk;
            float4 w4 = *(const float4*)&w2[(size_t)k * 128 + q * 4];
            float wc[4] = {w4.x, w4.y, w4.z, w4.w};
            float4 h4 = *(const float4*)&h1q[k * 4];
            float hr[4] = {h4.x, h4.y, h4.z, h4.w};
            #pragma unroll
            for (int r = 0; r < 4; ++r)
                #pragma unroll
                for (int c = 0; c < 4; ++c)
                    a2[r * 4 + c] = fmaf(hr[r], wc[c], a2[r * 4 + c]);
        }
        #pragma unroll
        for (int r = 0; r < 4; ++r)
            *(float4*)&part[u * 512 + r * 128 + q * 4] =
                make_float4(a2[r*4+0], a2[r*4+1], a2[r*4+2], a2[r*4+3]);
    }
    __syncthreads();
    {
        int r = t >> 7, f = t & 127;
        float s = b2[f];
        #pragma unroll
        for (int uu = 0; uu < 16; ++uu) s += part[uu * 512 + r * 128 + f];
        H[(size_t)(r0 + r) * 128 + f] = s;
    }
}

// ---------------------------------------------------------------------------
// k_gcn1: relation-mean aggregation + RGCN 3-matrix linear, fused.
// 512 threads; block = (b, 4 targets). Phase A i-slices of 16 per thread;
// two-pass rel combine keeps part at 32 KB. Weights direct from L2.
// Phase-B weight lines prefetched before phase A (2 per matrix, reg-cheap).
// ---------------------------------------------------------------------------
__global__ __launch_bounds__(512, 4) void k_gcn1(
        const float* __restrict__ A, const float* __restrict__ H,
        const float* __restrict__ Wrel, const float* __restrict__ Wroot,
        const float* __restrict__ bias, float* __restrict__ H2) {
    const int b  = blockIdx.x >> 6;
    const int j0 = (blockIdx.x & 63) * 4;
    const int t = threadIdx.x, q = t & 31, u = t >> 5;
    __shared__ __align__(16) float maskM[2048];  // [256][8]
    __shared__ __align__(16) float part[8192];   // [16u][4r][128f]
    __shared__ __align__(16) float pb[1536];     // [k][h4|m0_4|m1_4]
    __shared__ float cntp[256];
    __shared__ float cnt[8];
    const float* Ab = A + (size_t)b * 65536;
    const float* Hb = H + (size_t)b * 32768;
    const float* W0 = Wrel;
    const float* W1 = Wrel + 16384;

    {   // prefetch phase-B weight lines (k = u*8, u*8+4 per matrix)
        float pf = 0.f;
        #pragma unroll
        for (int kk = 0; kk < 8; kk += 4) {
            size_t off = (size_t)(u * 8 + kk) * 128 + q * 4;
            pf += Wroot[off] + W0[off] + W1[off];
        }
        KEEP(pf);
    }
    if (t < 256) {   // masks: thread t owns row i=t
        float4 a = *(const float4*)(Ab + (size_t)t * 256 + j0);
        float4 m0, m1;
        m0.x = (a.x < 0.f) ? 1.f : 0.f; m1.x = (a.x > 0.f) ? 1.f : 0.f;
        m0.y = (a.y < 0.f) ? 1.f : 0.f; m1.y = (a.y > 0.f) ? 1.f : 0.f;
        m0.z = (a.z < 0.f) ? 1.f : 0.f; m1.z = (a.z > 0.f) ? 1.f : 0.f;
        m0.w = (a.w < 0.f) ? 1.f : 0.f; m1.w = (a.w > 0.f) ? 1.f : 0.f;
        *(float4*)&maskM[t * 8]     = m0;
        *(float4*)&maskM[t * 8 + 4] = m1;
    }
    __syncthreads();
    if (t < 256) {   // count partials: 32 chunks x 8 slots
        int chunk = t >> 3, slot = t & 7;
        float c = 0.f;
        #pragma unroll
        for (int qq = 0; qq < 8; ++qq) c += maskM[(chunk * 8 + qq) * 8 + slot];
        cntp[slot * 32 + chunk] = c;
    }
    // phase A: thread sweeps i in [u*16, u*16+16), H direct from L2
    float acc0[16], acc1[16];
    #pragma unroll
    for (int i = 0; i < 16; ++i) { acc0[i] = 0.f; acc1[i] = 0.f; }
    #pragma unroll 8
    for (int ii = 0; ii < 16; ++ii) {
        int i = u * 16 + ii;
        float4 h4 = *(const float4*)&Hb[(size_t)i * 128 + q * 4];
        float hc[4] = {h4.x, h4.y, h4.z, h4.w};
        float4 m0 = *(const float4*)&maskM[i * 8];
        float4 m1 = *(const float4*)&maskM[i * 8 + 4];
        float mr0[4] = {m0.x, m0.y, m0.z, m0.w};
        float mr1[4] = {m1.x, m1.y, m1.z, m1.w};
        #pragma unroll
        for (int r = 0; r < 4; ++r)
            #pragma unroll
            for (int c = 0; c < 4; ++c) {
                acc0[r * 4 + c] = fmaf(mr0[r], hc[c], acc0[r * 4 + c]);
                acc1[r * 4 + c] = fmaf(mr1[r], hc[c], acc1[r * 4 + c]);
            }
    }
    // pass 1: rel0
    #pragma unroll
    for (int r = 0; r < 4; ++r)
        *(float4*)&part[u * 512 + r * 128 + q * 4] =
            make_float4(acc0[r*4+0], acc0[r*4+1], acc0[r*4+2], acc0[r*4+3]);
    if (t < 8) {
        float s = 0.f;
        #pragma unroll
        for (int c = 0; c < 32; ++c) s += cntp[t * 32 + c];
        cnt[t] = s;
    }
    __syncthreads();
    {
        int r = t >> 7, f = t & 127;
        float s = 0.f;
        #pragma unroll
        for (int uu = 0; uu < 16; ++uu) s += part[uu * 512 + r * 128 + f];
        pb[f * 12 + 4 + r] = s * (1.f / fmaxf(cnt[r], 1.f));
    }
    __syncthreads();
    // pass 2: rel1 + root rows
    #pragma unroll
    for (int r = 0; r < 4; ++r)
        *(float4*)&part[u * 512 + r * 128 + q * 4] =
            make_float4(acc1[r*4+0], acc1[r*4+1], acc1[r*4+2], acc1[r*4+3]);
    __syncthreads();
    {
        int r = t >> 7, f = t & 127;
        float s = 0.f;
        #pragma unroll
        for (int uu = 0; uu < 16; ++uu) s += part[uu * 512 + r * 128 + f];
        pb[f * 12 + 8 + r] = s * (1.f / fmaxf(cnt[4 + r], 1.f));
    }
    if (t < 128) {  // root rows -> pb
        int r = t >> 5, fq = t & 31;
        float4 g4 = *(const float4*)(Hb + (size_t)(j0 + r) * 128 + fq * 4);
        pb[(fq * 4 + 0) * 12 + r] = g4.x;
        pb[(fq * 4 + 1) * 12 + r] = g4.y;
        pb[(fq * 4 + 2) * 12 + r] = g4.z;
        pb[(fq * 4 + 3) * 12 + r] = g4.w;
    }
    __syncthreads();
    // phase B: K=128, thread covers k in [u*8, u*8+8), weights direct
    float bcc[16];
    #pragma unroll
    for (int i = 0; i < 16; ++i) bcc[i] = 0.f;
    #pragma unroll
    for (int kk = 0; kk < 8; ++kk) {
        int k = u * 8 + kk;
        float4 wr = *(const float4*)&Wroot[(size_t)k * 128 + q * 4];
        float4 wa = *(const float4*)&W0[(size_t)k * 128 + q * 4];
        float4 wb = *(const float4*)&W1[(size_t)k * 128 + q * 4];
        float wrc[4] = {wr.x, wr.y, wr.z, wr.w};
        float wac[4] = {wa.x, wa.y, wa.z, wa.w};
        float wbc[4] = {wb.x, wb.y, wb.z, wb.w};
        float4 hv = *(const float4*)&pb[k * 12];
        float4 q0 = *(const float4*)&pb[k * 12 + 4];
        float4 q1 = *(const float4*)&pb[k * 12 + 8];
        float hr[4] = {hv.x, hv.y, hv.z, hv.w};
        float m0r[4] = {q0.x, q0.y, q0.z, q0.w};
        float m1r[4] = {q1.x, q1.y, q1.z, q1.w};
        #pragma unroll
        for (int r = 0; r < 4; ++r)
            #pragma unroll
            for (int c = 0; c < 4; ++c) {
                float v = bcc[r * 4 + c];
                v = fmaf(hr[r], wrc[c], v);
                v = fmaf(m0r[r], wac[c], v);
                v = fmaf(m1r[r], wbc[c], v);
                bcc[r * 4 + c] = v;
            }
    }
    #pragma unroll
    for (int r = 0; r < 4; ++r)
        *(float4*)&part[u * 512 + r * 128 + q * 4] =
            make_float4(bcc[r*4+0], bcc[r*4+1], bcc[r*4+2], bcc[r*4+3]);
    __syncthreads();
    {
        int r = t >> 7, f = t & 127;
        float s = bias[f];
        #pragma unroll
        for (int uu = 0; uu < 16; ++uu) s += part[uu * 512 + r * 128 + f];
        H2[(size_t)(b * 256 + j0 + r) * 128 + f] = s;
    }
}

// ---------------------------------------------------------------------------
// k_gcn2: |A|-aggregation + LayerNorm + 2-layer MLP + H-update, fused.
// 512 threads; H2/weights direct from L2; LDS only for reductions.
// law/lbw lines prefetched before phase A; phase A fully unrolled (16 deep).
// ---------------------------------------------------------------------------
__global__ __launch_bounds__(512, 4) void k_gcn2(
        const float* __restrict__ A, const float* __restrict__ H2,
        const float* __restrict__ g, const float* __restrict__ bta,
        const float* __restrict__ law, const float* __restrict__ lab,
        const float* __restrict__ lbw, const float* __restrict__ lbb,
        float* __restrict__ H) {
    const int b  = blockIdx.x >> 6;
    const int i0 = (blockIdx.x & 63) * 4;
    const int t = threadIdx.x, q = t & 31, u = t >> 5;
    __shared__ __align__(16) float part[8192];   // [16u][4r][128f]
    __shared__ __align__(16) float absA[1024];   // [256][4]
    __shared__ __align__(16) float xq[512];      // [k][r]
    __shared__ __align__(16) float uq[512];      // [k][r]
    __shared__ float red[16];
    __shared__ float mi[8];
    const float* Ab  = A + (size_t)b * 65536;
    const float* H2b = H2 + (size_t)b * 32768;

    {   // prefetch MLP weight lines (k = u*8, u*8+4 per matrix)
        float pf = 0.f;
        #pragma unroll
        for (int kk = 0; kk < 8; kk += 4) {
            size_t off = (size_t)(u * 8 + kk) * 128 + q * 4;
            pf += law[off] + lbw[off];
        }
        KEEP(pf);
    }
    if (t < 256) {
        float4 av;
        av.x = fabsf(Ab[(size_t)(i0 + 0) * 256 + t]);
        av.y = fabsf(Ab[(size_t)(i0 + 1) * 256 + t]);
        av.z = fabsf(Ab[(size_t)(i0 + 2) * 256 + t]);
        av.w = fabsf(Ab[(size_t)(i0 + 3) * 256 + t]);
        *(float4*)&absA[t * 4] = av;
    }
    __syncthreads();
    // phase A: thread sweeps j in [u*16, u*16+16), fully unrolled (16-deep MLP)
    float acc[16];
    #pragma unroll
    for (int i = 0; i < 16; ++i) acc[i] = 0.f;
    #pragma unroll
    for (int jj = 0; jj < 16; ++jj) {
        int j = u * 16 + jj;
        float4 h4 = *(const float4*)&H2b[(size_t)j * 128 + q * 4];
        float hc[4] = {h4.x, h4.y, h4.z, h4.w};
        float4 a4 = *(const float4*)&absA[j * 4];
        float ar[4] = {a4.x, a4.y, a4.z, a4.w};
        #pragma unroll
        for (int r = 0; r < 4; ++r)
            #pragma unroll
            for (int c = 0; c < 4; ++c)
                acc[r * 4 + c] = fmaf(ar[r], hc[c], acc[r * 4 + c]);
    }
    #pragma unroll
    for (int r = 0; r < 4; ++r)
        *(float4*)&part[u * 512 + r * 128 + q * 4] =
            make_float4(acc[r*4+0], acc[r*4+1], acc[r*4+2], acc[r*4+3]);
    __syncthreads();
    // combine + LN: thread owns (r,f); row r = waves 2r,2r+1
    const int rr = t >> 7, ff = t & 127;
    float x;
    {
        float s = 0.f;
        #pragma unroll
        for (int uu = 0; uu < 16; ++uu) s += part[uu * 512 + rr * 128 + ff];
        x = s;
        float s2 = x * x;
        float sw = x;
        #pragma unroll
        for (int o = 32; o > 0; o >>= 1) {
            sw += __shfl_down(sw, o, 64);
            s2 += __shfl_down(s2, o, 64);
        }
        int w = (t >> 6) & 1;
        if ((t & 63) == 0) {
            red[(rr * 2 + w) * 2]     = sw;
            red[(rr * 2 + w) * 2 + 1] = s2;
        }
    }
    __syncthreads();
    if (t < 4) {
        float s  = red[t * 4]     + red[t * 4 + 2];
        float s2 = red[t * 4 + 1] + red[t * 4 + 3];
        float m = s * (1.f / 128.f);
        float v = s2 * (1.f / 128.f) - m * m;
        mi[t * 2] = m;
        mi[t * 2 + 1] = rsqrtf(v + 1e-5f);
    }
    __syncthreads();
    xq[ff * 4 + rr] = fmaxf((x - mi[rr * 2]) * mi[rr * 2 + 1] * g[ff] + bta[ff], 0.f);
    __syncthreads();
    // MLP layer A: K=128, thread covers k in [u*8, u*8+8)
    float u1[16];
    #pragma unroll
    for (int i = 0; i < 16; ++i) u1[i] = 0.f;
    #pragma unroll
    for (int kk = 0; kk < 8; ++kk) {
        int k = u * 8 + kk;
        float4 w4 = *(const float4*)&law[(size_t)k * 128 + q * 4];
        float wc[4] = {w4.x, w4.y, w4.z, w4.w};
        float4 x4 = *(const float4*)&xq[k * 4];
        float xr[4] = {x4.x, x4.y, x4.z, x4.w};
        #pragma unroll
        for (int r = 0; r < 4; ++r)
            #pragma unroll
            for (int c = 0; c < 4; ++c)
                u1[r * 4 + c] = fmaf(xr[r], wc[c], u1[r * 4 + c]);
    }
    #pragma unroll
    for (int r = 0; r < 4; ++r)
        *(float4*)&part[u * 512 + r * 128 + q * 4] =
            make_float4(u1[r*4+0], u1[r*4+1], u1[r*4+2], u1[r*4+3]);
    __syncthreads();
    {
        float s = lab[ff];
        #pragma unroll
        for (int uu = 0; uu < 16; ++uu) s += part[uu * 512 + rr * 128 + ff];
        uq[ff * 4 + rr] = fmaxf(s, 0.f);
    }
    __syncthreads();
    // MLP layer B: K=128
    float u2[16];
    #pragma unroll
    for (int i = 0; i < 16; ++i) u2[i] = 0.f;
    #pragma unroll
    for (int kk = 0; kk < 8; ++kk) {
        int k = u * 8 + kk;
        float4 w4 = *(const float4*)&lbw[(size_t)k * 128 + q * 4];
        float wc[4] = {w4.x, w4.y, w4.z, w4.w};
        float4 x4 = *(const float4*)&uq[k * 4];
        float xr[4] = {x4.x, x4.y, x4.z, x4.w};
        #pragma unroll
        for (int r = 0; r < 4; ++r)
            #pragma unroll
            for (int c = 0; c < 4; ++c)
                u2[r * 4 + c] = fmaf(xr[r], wc[c], u2[r * 4 + c]);
    }
    #pragma unroll
    for (int r = 0; r < 4; ++r)
        *(float4*)&part[u * 512 + r * 128 + q * 4] =
            make_float4(u2[r*4+0], u2[r*4+1], u2[r*4+2], u2[r*4+3]);
    __syncthreads();
    {
        float s = lbb[ff];
        #pragma unroll
        for (int uu = 0; uu < 16; ++uu) s += part[uu * 512 + rr * 128 + ff];
        size_t idx = (size_t)(b * 256 + i0 + rr) * 128 + ff;
        H[idx] = s + H[idx];
    }
}

// ---------------------------------------------------------------------------
// k_deepset: phi (128->256->256 relu) + masked pooling. 4 rows/block,
// grid 512, 512 threads. q = t&63 (f-quad of 256), u = t>>6 (K-slice of 8).
// Weights direct from L2; both sweeps fully unrolled (16-deep MLP);
// w1/w2 lines prefetched at top.
// ---------------------------------------------------------------------------
__global__ __launch_bounds__(512, 4) void k_deepset(
        const float* __restrict__ H, const float* __restrict__ hm,
        const float* __restrict__ w1, const float* __restrict__ b1,
        const float* __restrict__ w2, const float* __restrict__ b2,
        float* __restrict__ hsum, float* __restrict__ asum) {
    const int r0 = blockIdx.x * 4;
    const int b  = blockIdx.x >> 6;
    const int t  = threadIdx.x, q = t & 63, u = t >> 6;
    __shared__ __align__(16) float part[8192];   // [8u][4r][256f]
    __shared__ __align__(16) float ph2[1024];    // [r][256]
    __shared__ __align__(16) float hraw[512];    // [r][128]
    __shared__ float hmv[4];
    {   // prefetch w1 (k=u*16, stride 4) and w2 (k=u*32, stride 8) lines
        float pf = 0.f;
        #pragma unroll
        for (int kk = 0; kk < 16; kk += 4)
            pf += w1[(size_t)(u * 16 + kk) * 256 + q * 4];
        #pragma unroll
        for (int kk = 0; kk < 32; kk += 8)
            pf += w2[(size_t)(u * 32 + kk) * 256 + q * 4];
        KEEP(pf);
    }
    if (t < 128) {
        float4 g4 = *(const float4*)&H[(size_t)r0 * 128 + t * 4];
        *(float4*)&hraw[t * 4] = g4;
    }
    if (t < 4) hmv[t] = hm[r0 + t];
    __syncthreads();
    // L1: K=128, thread covers k in [u*16, u*16+16), fully unrolled
    float acc[16];
    #pragma unroll
    for (int i = 0; i < 16; ++i) acc[i] = 0.f;
    #pragma unroll
    for (int kk = 0; kk < 16; ++kk) {
        int k = u * 16 + kk;
        float4 w4 = *(const float4*)&w1[(size_t)k * 256 + q * 4];
        float wc[4] = {w4.x, w4.y, w4.z, w4.w};
        float hr[4];
        #pragma unroll
        for (int r = 0; r < 4; ++r) hr[r] = hraw[r * 128 + k];
        #pragma unroll
        for (int r = 0; r < 4; ++r)
            #pragma unroll
            for (int c = 0; c < 4; ++c)
                acc[r * 4 + c] = fmaf(hr[r], wc[c], acc[r * 4 + c]);
    }
    #pragma unroll
    for (int r = 0; r < 4; ++r)
        *(float4*)&part[u * 1024 + r * 256 + q * 4] =
            make_float4(acc[r*4+0], acc[r*4+1], acc[r*4+2], acc[r*4+3]);
    __syncthreads();
    {   // combine L1 -> ph2 (relu): 1024 outputs, 2 per thread
        #pragma unroll
        for (int e = 0; e < 2; ++e) {
            int idx = e * 512 + t;
            int r = idx >> 8, f = idx & 255;
            float s = b1[f];
            #pragma unroll
            for (int uu = 0; uu < 8; ++uu) s += part[uu * 1024 + r * 256 + f];
            ph2[r * 256 + f] = fmaxf(s, 0.f);
        }
    }
    __syncthreads();
    // L2: K=256, thread covers k in [u*32, u*32+32), 16-deep unroll
    float a2[16];
    #pragma unroll
    for (int i = 0; i < 16; ++i) a2[i] = 0.f;
    #pragma unroll 16
    for (int kk = 0; kk < 32; ++kk) {
        int k = u * 32 + kk;
        float4 w4 = *(const float4*)&w2[(size_t)k * 256 + q * 4];
        float wc[4] = {w4.x, w4.y, w4.z, w4.w};
        float pv[4];
        #pragma unroll
        for (int r = 0; r < 4; ++r) pv[r] = ph2[r * 256 + k];
        #pragma unroll
        for (int r = 0; r < 4; ++r)
            #pragma unroll
            for (int c = 0; c < 4; ++c)
                a2[r * 4 + c] = fmaf(pv[r], wc[c], a2[r * 4 + c]);
    }
    __syncthreads();
    #pragma unroll
    for (int r = 0; r < 4; ++r)
        *(float4*)&part[u * 1024 + r * 256 + q * 4] =
            make_float4(a2[r*4+0], a2[r*4+1], a2[r*4+2], a2[r*4+3]);
    __syncthreads();
    if (t < 256) {   // final combine + relu + masked pool (f = t)
        float bb = b2[t];
        float hp = 0.f, sp = 0.f;
        #pragma unroll
        for (int r = 0; r < 4; ++r) {
            float s = bb;
            #pragma unroll
            for (int uu = 0; uu < 8; ++uu) s += part[uu * 1024 + r * 256 + t];
            float p = fmaxf(s, 0.f);
            sp += p;
            hp = fmaf(p, hmv[r], hp);
        }
        atomicAdd(&hsum[b * 256 + t], hp);
        atomicAdd(&asum[b * 256 + t], sp - hp);
    }
}

// ---------------------------------------------------------------------------
// k_rho: out[b] = 0.5 + 0.5*tanh(rho(home)-rho(away)); b2 cancels.
// ---------------------------------------------------------------------------
__global__ __launch_bounds__(256) void k_rho(const float* __restrict__ hsum,
        const float* __restrict__ asum,
        const float* __restrict__ w1, const float* __restrict__ b1,
        const float* __restrict__ w2, const float* __restrict__ b2,
        float* __restrict__ out) {
    const int bIdx = blockIdx.x;
    const int t = threadIdx.x, q = t & 31, u = t >> 5;
    __shared__ __align__(16) float part[2048];
    __shared__ __align__(16) float sv[512];
    __shared__ float wsv[2];
    sv[t] = hsum[bIdx * 256 + t];
    sv[256 + t] = asum[bIdx * 256 + t];
    __syncthreads();
    float aH[4] = {0.f, 0.f, 0.f, 0.f}, aA[4] = {0.f, 0.f, 0.f, 0.f};
    #pragma unroll 16
    for (int kk = 0; kk < 32; ++kk) {
        int k = u * 32 + kk;
        float4 w4 = *(const float4*)&w1[(size_t)k * 128 + q * 4];
        float sh = sv[k], sa = sv[256 + k];
        aH[0] = fmaf(sh, w4.x, aH[0]); aA[0] = fmaf(sa, w4.x, aA[0]);
        aH[1] = fmaf(sh, w4.y, aH[1]); aA[1] = fmaf(sa, w4.y, aA[1]);
        aH[2] = fmaf(sh, w4.z, aH[2]); aA[2] = fmaf(sa, w4.z, aA[2]);
        aH[3] = fmaf(sh, w4.w, aH[3]); aA[3] = fmaf(sa, w4.w, aA[3]);
    }
    *(float4*)&part[u * 256 + q * 4]       = make_float4(aH[0], aH[1], aH[2], aH[3]);
    *(float4*)&part[u * 256 + 128 + q * 4] = make_float4(aA[0], aA[1], aA[2], aA[3]);
    __syncthreads();
    if (t < 64) {
        int vec = t >> 5, fq = t & 31;
        float4 s = make_float4(0.f, 0.f, 0.f, 0.f);
        #pragma unroll
        for (int uu = 0; uu < 8; ++uu) {
            float4 p = *(const float4*)&part[uu * 256 + vec * 128 + fq * 4];
            s.x += p.x; s.y += p.y; s.z += p.z; s.w += p.w;
        }
        float4 bb = *(const float4*)&b1[fq * 4];
        float4 w2q = *(const float4*)&w2[fq * 4];
        float p = fmaxf(s.x + bb.x, 0.f) * w2q.x
                + fmaxf(s.y + bb.y, 0.f) * w2q.y
                + fmaxf(s.z + bb.z, 0.f) * w2q.z
                + fmaxf(s.w + bb.w, 0.f) * w2q.w;
        #pragma unroll
        for (int o = 16; o > 0; o >>= 1) p += __shfl_down(p, o, 32);
        if ((t & 31) == 0) wsv[vec] = p;
    }
    __syncthreads();
    if (t == 0) out[bIdx] = 0.5f + 0.5f * tanhf(wsv[0] - wsv[1]);
}

// ---------------------------------------------------------------------------
extern "C" void kernel_launch(void* const* d_in, const int* in_sizes, int n_in,
                              void* d_out, int out_size, void* d_ws, size_t ws_size,
                              hipStream_t stream) {
    const float* A         = (const float*)d_in[0];
    const float* X         = (const float*)d_in[1];
    const float* home_mask = (const float*)d_in[2];
    const float* emb1_w    = (const float*)d_in[3];
    const float* emb1_b    = (const float*)d_in[4];
    const float* emb2_w    = (const float*)d_in[5];
    const float* emb2_b    = (const float*)d_in[6];
    const float* rgcn_w[2]    = { (const float*)d_in[7],  (const float*)d_in[14] };
    const float* rgcn_root[2] = { (const float*)d_in[8],  (const float*)d_in[15] };
    const float* rgcn_bias[2] = { (const float*)d_in[9],  (const float*)d_in[16] };
    const float* lina_w[2]    = { (const float*)d_in[10], (const float*)d_in[17] };
    const float* lina_b[2]    = { (const float*)d_in[11], (const float*)d_in[18] };
    const float* linb_w[2]    = { (const float*)d_in[12], (const float*)d_in[19] };
    const float* linb_b[2]    = { (const float*)d_in[13], (const float*)d_in[20] };
    const float* norm_g  = (const float*)d_in[21];
    const float* norm_b  = (const float*)d_in[22];
    const float* phi_w1  = (const float*)d_in[23];
    const float* phi_b1  = (const float*)d_in[24];
    const float* phi_w2  = (const float*)d_in[25];
    const float* phi_b2  = (const float*)d_in[26];
    const float* rho_w1  = (const float*)d_in[27];
    const float* rho_b1  = (const float*)d_in[28];
    const float* rho_w2  = (const float*)d_in[29];
    const float* rho_b2  = (const float*)d_in[30];
    float* out = (float*)d_out;

    float* ws   = (float*)d_ws;
    float* H    = ws;               // 262144
    float* H2   = ws + 262144;      // 262144
    float* hsum = ws + 524288;      // 2048
    float* asum = ws + 526336;      // 2048 (contiguous with hsum)

    k_embed<<<512, 512, 0, stream>>>(X, emb1_w, emb1_b, emb2_w, emb2_b, H, hsum);

    for (int it = 0; it < 2; ++it) {
        k_gcn1<<<512, 512, 0, stream>>>(A, H, rgcn_w[it], rgcn_root[it],
                                        rgcn_bias[it], H2);
        k_gcn2<<<512, 512, 0, stream>>>(A, H2, norm_g, norm_b,
                                        lina_w[it], lina_b[it],
                                        linb_w[it], linb_b[it], H);
    }

    k_deepset<<<512, 512, 0, stream>>>(H, home_mask, phi_w1, phi_b1,
                                       phi_w2, phi_b2, hsum, asum);
    k_rho<<<NB, 256, 0, stream>>>(hsum, asum, rho_w1, rho_b1, rho_w2, rho_b2, out);
}

// Round 9
// 181.254 us; speedup vs baseline: 1.1181x; 1.0057x over previous
//
#include <hip/hip_runtime.h>
#include <math.h>

// Shapes: B=8, N=256, NID=64, V=GH=128, PHI=256, RHO=128
#define NB 8

#define KEEP(x) asm volatile("" :: "v"(x))

// Chain-warming: touch one 128B line per participating thread of the NEXT
// kernel's weight array, pulling it into L2/L3 under this kernel's compute.
static __device__ __forceinline__ void warm(const float* p, int nfloats,
                                            int gtid) {
    int lines = nfloats >> 5;            // 32 floats per 128B line
    if (gtid < lines) {
        float v = p[(size_t)gtid * 32];
        KEEP(v);
    }
}

// ---------------------------------------------------------------------------
// k_embed: H = relu(X@w1+b1)@w2+b2. 4 rows/block, grid 512, 512 threads.
// q = t&31 (f-quad of 128), u = t>>5 (K-slice of 16). Direct-from-L2 weights.
// w2 lines prefetched during L1; warms gcn1-it0 weights for the next kernel.
// ---------------------------------------------------------------------------
__global__ __launch_bounds__(512, 4) void k_embed(const float* __restrict__ X,
        const float* __restrict__ w1, const float* __restrict__ b1,
        const float* __restrict__ w2, const float* __restrict__ b2,
        float* __restrict__ H, float* __restrict__ pools,
        const float* __restrict__ wa, int na,
        const float* __restrict__ wb, int nb) {
    const int r0 = blockIdx.x * 4;
    const int t = threadIdx.x, q = t & 31, u = t >> 5;
    const int gtid = blockIdx.x * 512 + t;
    __shared__ __align__(16) float part[8192];   // [16u][4r][128f]
    __shared__ __align__(16) float xq[256];      // [k][r]
    __shared__ __align__(16) float h1q[512];     // [k][r]
    if (blockIdx.x < 8) pools[blockIdx.x * 512 + t] = 0.f;
    {   // prefetch future w2 lines (k = u*8 .. +8, stride 2) -> warm L2/L1
        float pf = 0.f;
        #pragma unroll
        for (int kk = 0; kk < 8; kk += 2)
            pf += w2[(size_t)(u * 8 + kk) * 128 + q * 4];
        KEEP(pf);
    }
    warm(wa, na, gtid);
    warm(wb, nb, gtid);
    if (t < 64) {
        float4 v;
        v.x = X[(size_t)(r0 + 0) * 64 + t];
        v.y = X[(size_t)(r0 + 1) * 64 + t];
        v.z = X[(size_t)(r0 + 2) * 64 + t];
        v.w = X[(size_t)(r0 + 3) * 64 + t];
        *(float4*)&xq[t * 4] = v;
    }
    __syncthreads();
    {   // L1: K=64, thread covers k in [u*4, u*4+4)
        float acc[16];
        #pragma unroll
        for (int i = 0; i < 16; ++i) acc[i] = 0.f;
        #pragma unroll
        for (int kk = 0; kk < 4; ++kk) {
            int k = u * 4 + kk;
            float4 w4 = *(const float4*)&w1[(size_t)k * 128 + q * 4];
            float wc[4] = {w4.x, w4.y, w4.z, w4.w};
            float4 x4 = *(const float4*)&xq[k * 4];
            float xr[4] = {x4.x, x4.y, x4.z, x4.w};
            #pragma unroll
            for (int r = 0; r < 4; ++r)
                #pragma unroll
                for (int c = 0; c < 4; ++c)
                    acc[r * 4 + c] = fmaf(xr[r], wc[c], acc[r * 4 + c]);
        }
        #pragma unroll
        for (int r = 0; r < 4; ++r)
            *(float4*)&part[u * 512 + r * 128 + q * 4] =
                make_float4(acc[r*4+0], acc[r*4+1], acc[r*4+2], acc[r*4+3]);
    }
    __syncthreads();
    {   // combine -> h1q: thread owns (r,f)
        int r = t >> 7, f = t & 127;
        float s = b1[f];
        #pragma unroll
        for (int uu = 0; uu < 16; ++uu) s += part[uu * 512 + r * 128 + f];
        h1q[f * 4 + r] = fmaxf(s, 0.f);
    }
    __syncthreads();
    {   // L2: K=128, thread covers k in [u*8, u*8+8)
        float a2[16];
        #pragma unroll
        for (int i = 0; i < 16; ++i) a2[i] = 0.f;
        #pragma unroll
        for (int kk = 0; kk < 8; ++kk) {
            int k = u * 8 + kk;
            float4 w4 = *(const float4*)&w2[(size_t)k * 128 + q * 4];
            float wc[4] = {w4.x, w4.y, w4.z, w4.w};
            float4 h4 = *(const float4*)&h1q[k * 4];
            float hr[4] = {h4.x, h4.y, h4.z, h4.w};
            #pragma unroll
            for (int r = 0; r < 4; ++r)
                #pragma unroll
                for (int c = 0; c < 4; ++c)
                    a2[r * 4 + c] = fmaf(hr[r], wc[c], a2[r * 4 + c]);
        }
        #pragma unroll
        for (int r = 0; r < 4; ++r)
            *(float4*)&part[u * 512 + r * 128 + q * 4] =
                make_float4(a2[r*4+0], a2[r*4+1], a2[r*4+2], a2[r*4+3]);
    }
    __syncthreads();
    {
        int r = t >> 7, f = t & 127;
        float s = b2[f];
        #pragma unroll
        for (int uu = 0; uu < 16; ++uu) s += part[uu * 512 + r * 128 + f];
        H[(size_t)(r0 + r) * 128 + f] = s;
    }
}

// ---------------------------------------------------------------------------
// k_gcn1: relation-mean aggregation + RGCN 3-matrix linear, fused.
// 512 threads; block = (b, 4 targets). Phase A i-slices of 16 per thread;
// two-pass rel combine keeps part at 32 KB. Weights direct from L2.
// Phase-B weight lines prefetched before phase A; warms next kernel's weights.
// ---------------------------------------------------------------------------
__global__ __launch_bounds__(512, 4) void k_gcn1(
        const float* __restrict__ A, const float* __restrict__ H,
        const float* __restrict__ Wrel, const float* __restrict__ Wroot,
        const float* __restrict__ bias, float* __restrict__ H2,
        const float* __restrict__ wa, int na,
        const float* __restrict__ wb, int nb) {
    const int b  = blockIdx.x >> 6;
    const int j0 = (blockIdx.x & 63) * 4;
    const int t = threadIdx.x, q = t & 31, u = t >> 5;
    const int gtid = blockIdx.x * 512 + t;
    __shared__ __align__(16) float maskM[2048];  // [256][8]
    __shared__ __align__(16) float part[8192];   // [16u][4r][128f]
    __shared__ __align__(16) float pb[1536];     // [k][h4|m0_4|m1_4]
    __shared__ float cntp[256];
    __shared__ float cnt[8];
    const float* Ab = A + (size_t)b * 65536;
    const float* Hb = H + (size_t)b * 32768;
    const float* W0 = Wrel;
    const float* W1 = Wrel + 16384;

    {   // prefetch phase-B weight lines (k = u*8, u*8+4 per matrix)
        float pf = 0.f;
        #pragma unroll
        for (int kk = 0; kk < 8; kk += 4) {
            size_t off = (size_t)(u * 8 + kk) * 128 + q * 4;
            pf += Wroot[off] + W0[off] + W1[off];
        }
        KEEP(pf);
    }
    warm(wa, na, gtid);
    warm(wb, nb, gtid);
    if (t < 256) {   // masks: thread t owns row i=t
        float4 a = *(const float4*)(Ab + (size_t)t * 256 + j0);
        float4 m0, m1;
        m0.x = (a.x < 0.f) ? 1.f : 0.f; m1.x = (a.x > 0.f) ? 1.f : 0.f;
        m0.y = (a.y < 0.f) ? 1.f : 0.f; m1.y = (a.y > 0.f) ? 1.f : 0.f;
        m0.z = (a.z < 0.f) ? 1.f : 0.f; m1.z = (a.z > 0.f) ? 1.f : 0.f;
        m0.w = (a.w < 0.f) ? 1.f : 0.f; m1.w = (a.w > 0.f) ? 1.f : 0.f;
        *(float4*)&maskM[t * 8]     = m0;
        *(float4*)&maskM[t * 8 + 4] = m1;
    }
    __syncthreads();
    if (t < 256) {   // count partials: 32 chunks x 8 slots
        int chunk = t >> 3, slot = t & 7;
        float c = 0.f;
        #pragma unroll
        for (int qq = 0; qq < 8; ++qq) c += maskM[(chunk * 8 + qq) * 8 + slot];
        cntp[slot * 32 + chunk] = c;
    }
    // phase A: thread sweeps i in [u*16, u*16+16), H direct from L2
    float acc0[16], acc1[16];
    #pragma unroll
    for (int i = 0; i < 16; ++i) { acc0[i] = 0.f; acc1[i] = 0.f; }
    #pragma unroll 8
    for (int ii = 0; ii < 16; ++ii) {
        int i = u * 16 + ii;
        float4 h4 = *(const float4*)&Hb[(size_t)i * 128 + q * 4];
        float hc[4] = {h4.x, h4.y, h4.z, h4.w};
        float4 m0 = *(const float4*)&maskM[i * 8];
        float4 m1 = *(const float4*)&maskM[i * 8 + 4];
        float mr0[4] = {m0.x, m0.y, m0.z, m0.w};
        float mr1[4] = {m1.x, m1.y, m1.z, m1.w};
        #pragma unroll
        for (int r = 0; r < 4; ++r)
            #pragma unroll
            for (int c = 0; c < 4; ++c) {
                acc0[r * 4 + c] = fmaf(mr0[r], hc[c], acc0[r * 4 + c]);
                acc1[r * 4 + c] = fmaf(mr1[r], hc[c], acc1[r * 4 + c]);
            }
    }
    // pass 1: rel0
    #pragma unroll
    for (int r = 0; r < 4; ++r)
        *(float4*)&part[u * 512 + r * 128 + q * 4] =
            make_float4(acc0[r*4+0], acc0[r*4+1], acc0[r*4+2], acc0[r*4+3]);
    if (t < 8) {
        float s = 0.f;
        #pragma unroll
        for (int c = 0; c < 32; ++c) s += cntp[t * 32 + c];
        cnt[t] = s;
    }
    __syncthreads();
    {
        int r = t >> 7, f = t & 127;
        float s = 0.f;
        #pragma unroll
        for (int uu = 0; uu < 16; ++uu) s += part[uu * 512 + r * 128 + f];
        pb[f * 12 + 4 + r] = s * (1.f / fmaxf(cnt[r], 1.f));
    }
    __syncthreads();
    // pass 2: rel1 + root rows
    #pragma unroll
    for (int r = 0; r < 4; ++r)
        *(float4*)&part[u * 512 + r * 128 + q * 4] =
            make_float4(acc1[r*4+0], acc1[r*4+1], acc1[r*4+2], acc1[r*4+3]);
    __syncthreads();
    {
        int r = t >> 7, f = t & 127;
        float s = 0.f;
        #pragma unroll
        for (int uu = 0; uu < 16; ++uu) s += part[uu * 512 + r * 128 + f];
        pb[f * 12 + 8 + r] = s * (1.f / fmaxf(cnt[4 + r], 1.f));
    }
    if (t < 128) {  // root rows -> pb
        int r = t >> 5, fq = t & 31;
        float4 g4 = *(const float4*)(Hb + (size_t)(j0 + r) * 128 + fq * 4);
        pb[(fq * 4 + 0) * 12 + r] = g4.x;
        pb[(fq * 4 + 1) * 12 + r] = g4.y;
        pb[(fq * 4 + 2) * 12 + r] = g4.z;
        pb[(fq * 4 + 3) * 12 + r] = g4.w;
    }
    __syncthreads();
    // phase B: K=128, thread covers k in [u*8, u*8+8), weights direct
    float bcc[16];
    #pragma unroll
    for (int i = 0; i < 16; ++i) bcc[i] = 0.f;
    #pragma unroll
    for (int kk = 0; kk < 8; ++kk) {
        int k = u * 8 + kk;
        float4 wr = *(const float4*)&Wroot[(size_t)k * 128 + q * 4];
        float4 wa4 = *(const float4*)&W0[(size_t)k * 128 + q * 4];
        float4 wb4 = *(const float4*)&W1[(size_t)k * 128 + q * 4];
        float wrc[4] = {wr.x, wr.y, wr.z, wr.w};
        float wac[4] = {wa4.x, wa4.y, wa4.z, wa4.w};
        float wbc[4] = {wb4.x, wb4.y, wb4.z, wb4.w};
        float4 hv = *(const float4*)&pb[k * 12];
        float4 q0 = *(const float4*)&pb[k * 12 + 4];
        float4 q1 = *(const float4*)&pb[k * 12 + 8];
        float hr[4] = {hv.x, hv.y, hv.z, hv.w};
        float m0r[4] = {q0.x, q0.y, q0.z, q0.w};
        float m1r[4] = {q1.x, q1.y, q1.z, q1.w};
        #pragma unroll
        for (int r = 0; r < 4; ++r)
            #pragma unroll
            for (int c = 0; c < 4; ++c) {
                float v = bcc[r * 4 + c];
                v = fmaf(hr[r], wrc[c], v);
                v = fmaf(m0r[r], wac[c], v);
                v = fmaf(m1r[r], wbc[c], v);
                bcc[r * 4 + c] = v;
            }
    }
    #pragma unroll
    for (int r = 0; r < 4; ++r)
        *(float4*)&part[u * 512 + r * 128 + q * 4] =
            make_float4(bcc[r*4+0], bcc[r*4+1], bcc[r*4+2], bcc[r*4+3]);
    __syncthreads();
    {
        int r = t >> 7, f = t & 127;
        float s = bias[f];
        #pragma unroll
        for (int uu = 0; uu < 16; ++uu) s += part[uu * 512 + r * 128 + f];
        H2[(size_t)(b * 256 + j0 + r) * 128 + f] = s;
    }
}

// ---------------------------------------------------------------------------
// k_gcn2: |A|-aggregation + LayerNorm + 2-layer MLP + H-update, fused.
// 512 threads; H2/weights direct from L2; LDS only for reductions.
// law/lbw lines prefetched before phase A; warms next kernel's weights.
// ---------------------------------------------------------------------------
__global__ __launch_bounds__(512, 4) void k_gcn2(
        const float* __restrict__ A, const float* __restrict__ H2,
        const float* __restrict__ g, const float* __restrict__ bta,
        const float* __restrict__ law, const float* __restrict__ lab,
        const float* __restrict__ lbw, const float* __restrict__ lbb,
        float* __restrict__ H,
        const float* __restrict__ wa, int na,
        const float* __restrict__ wb, int nb) {
    const int b  = blockIdx.x >> 6;
    const int i0 = (blockIdx.x & 63) * 4;
    const int t = threadIdx.x, q = t & 31, u = t >> 5;
    const int gtid = blockIdx.x * 512 + t;
    __shared__ __align__(16) float part[8192];   // [16u][4r][128f]
    __shared__ __align__(16) float absA[1024];   // [256][4]
    __shared__ __align__(16) float xq[512];      // [k][r]
    __shared__ __align__(16) float uq[512];      // [k][r]
    __shared__ float red[16];
    __shared__ float mi[8];
    const float* Ab  = A + (size_t)b * 65536;
    const float* H2b = H2 + (size_t)b * 32768;

    {   // prefetch MLP weight lines (k = u*8, u*8+4 per matrix)
        float pf = 0.f;
        #pragma unroll
        for (int kk = 0; kk < 8; kk += 4) {
            size_t off = (size_t)(u * 8 + kk) * 128 + q * 4;
            pf += law[off] + lbw[off];
        }
        KEEP(pf);
    }
    warm(wa, na, gtid);
    warm(wb, nb, gtid);
    if (t < 256) {
        float4 av;
        av.x = fabsf(Ab[(size_t)(i0 + 0) * 256 + t]);
        av.y = fabsf(Ab[(size_t)(i0 + 1) * 256 + t]);
        av.z = fabsf(Ab[(size_t)(i0 + 2) * 256 + t]);
        av.w = fabsf(Ab[(size_t)(i0 + 3) * 256 + t]);
        *(float4*)&absA[t * 4] = av;
    }
    __syncthreads();
    // phase A: thread sweeps j in [u*16, u*16+16), fully unrolled (16-deep MLP)
    float acc[16];
    #pragma unroll
    for (int i = 0; i < 16; ++i) acc[i] = 0.f;
    #pragma unroll
    for (int jj = 0; jj < 16; ++jj) {
        int j = u * 16 + jj;
        float4 h4 = *(const float4*)&H2b[(size_t)j * 128 + q * 4];
        float hc[4] = {h4.x, h4.y, h4.z, h4.w};
        float4 a4 = *(const float4*)&absA[j * 4];
        float ar[4] = {a4.x, a4.y, a4.z, a4.w};
        #pragma unroll
        for (int r = 0; r < 4; ++r)
            #pragma unroll
            for (int c = 0; c < 4; ++c)
                acc[r * 4 + c] = fmaf(ar[r], hc[c], acc[r * 4 + c]);
    }
    #pragma unroll
    for (int r = 0; r < 4; ++r)
        *(float4*)&part[u * 512 + r * 128 + q * 4] =
            make_float4(acc[r*4+0], acc[r*4+1], acc[r*4+2], acc[r*4+3]);
    __syncthreads();
    // combine + LN: thread owns (r,f); row r = waves 2r,2r+1
    const int rr = t >> 7, ff = t & 127;
    float x;
    {
        float s = 0.f;
        #pragma unroll
        for (int uu = 0; uu < 16; ++uu) s += part[uu * 512 + rr * 128 + ff];
        x = s;
        float s2 = x * x;
        float sw = x;
        #pragma unroll
        for (int o = 32; o > 0; o >>= 1) {
            sw += __shfl_down(sw, o, 64);
            s2 += __shfl_down(s2, o, 64);
        }
        int w = (t >> 6) & 1;
        if ((t & 63) == 0) {
            red[(rr * 2 + w) * 2]     = sw;
            red[(rr * 2 + w) * 2 + 1] = s2;
        }
    }
    __syncthreads();
    if (t < 4) {
        float s  = red[t * 4]     + red[t * 4 + 2];
        float s2 = red[t * 4 + 1] + red[t * 4 + 3];
        float m = s * (1.f / 128.f);
        float v = s2 * (1.f / 128.f) - m * m;
        mi[t * 2] = m;
        mi[t * 2 + 1] = rsqrtf(v + 1e-5f);
    }
    __syncthreads();
    xq[ff * 4 + rr] = fmaxf((x - mi[rr * 2]) * mi[rr * 2 + 1] * g[ff] + bta[ff], 0.f);
    __syncthreads();
    // MLP layer A: K=128, thread covers k in [u*8, u*8+8)
    float u1[16];
    #pragma unroll
    for (int i = 0; i < 16; ++i) u1[i] = 0.f;
    #pragma unroll
    for (int kk = 0; kk < 8; ++kk) {
        int k = u * 8 + kk;
        float4 w4 = *(const float4*)&law[(size_t)k * 128 + q * 4];
        float wc[4] = {w4.x, w4.y, w4.z, w4.w};
        float4 x4 = *(const float4*)&xq[k * 4];
        float xr[4] = {x4.x, x4.y, x4.z, x4.w};
        #pragma unroll
        for (int r = 0; r < 4; ++r)
            #pragma unroll
            for (int c = 0; c < 4; ++c)
                u1[r * 4 + c] = fmaf(xr[r], wc[c], u1[r * 4 + c]);
    }
    #pragma unroll
    for (int r = 0; r < 4; ++r)
        *(float4*)&part[u * 512 + r * 128 + q * 4] =
            make_float4(u1[r*4+0], u1[r*4+1], u1[r*4+2], u1[r*4+3]);
    __syncthreads();
    {
        float s = lab[ff];
        #pragma unroll
        for (int uu = 0; uu < 16; ++uu) s += part[uu * 512 + rr * 128 + ff];
        uq[ff * 4 + rr] = fmaxf(s, 0.f);
    }
    __syncthreads();
    // MLP layer B: K=128
    float u2[16];
    #pragma unroll
    for (int i = 0; i < 16; ++i) u2[i] = 0.f;
    #pragma unroll
    for (int kk = 0; kk < 8; ++kk) {
        int k = u * 8 + kk;
        float4 w4 = *(const float4*)&lbw[(size_t)k * 128 + q * 4];
        float wc[4] = {w4.x, w4.y, w4.z, w4.w};
        float4 x4 = *(const float4*)&uq[k * 4];
        float xr[4] = {x4.x, x4.y, x4.z, x4.w};
        #pragma unroll
        for (int r = 0; r < 4; ++r)
            #pragma unroll
            for (int c = 0; c < 4; ++c)
                u2[r * 4 + c] = fmaf(xr[r], wc[c], u2[r * 4 + c]);
    }
    #pragma unroll
    for (int r = 0; r < 4; ++r)
        *(float4*)&part[u * 512 + r * 128 + q * 4] =
            make_float4(u2[r*4+0], u2[r*4+1], u2[r*4+2], u2[r*4+3]);
    __syncthreads();
    {
        float s = lbb[ff];
        #pragma unroll
        for (int uu = 0; uu < 16; ++uu) s += part[uu * 512 + rr * 128 + ff];
        size_t idx = (size_t)(b * 256 + i0 + rr) * 128 + ff;
        H[idx] = s + H[idx];
    }
}

// ---------------------------------------------------------------------------
// k_deepset: phi (128->256->256 relu) + masked pooling. 4 rows/block,
// grid 512, 512 threads. q = t&63 (f-quad of 256), u = t>>6 (K-slice of 8).
// Weights direct from L2; both sweeps deeply unrolled; w1/w2 lines
// prefetched at top; warms rho weights for the final kernel.
// ---------------------------------------------------------------------------
__global__ __launch_bounds__(512, 4) void k_deepset(
        const float* __restrict__ H, const float* __restrict__ hm,
        const float* __restrict__ w1, const float* __restrict__ b1,
        const float* __restrict__ w2, const float* __restrict__ b2,
        float* __restrict__ hsum, float* __restrict__ asum,
        const float* __restrict__ wa, int na) {
    const int r0 = blockIdx.x * 4;
    const int b  = blockIdx.x >> 6;
    const int t  = threadIdx.x, q = t & 63, u = t >> 6;
    const int gtid = blockIdx.x * 512 + t;
    __shared__ __align__(16) float part[8192];   // [8u][4r][256f]
    __shared__ __align__(16) float ph2[1024];    // [r][256]
    __shared__ __align__(16) float hraw[512];    // [r][128]
    __shared__ float hmv[4];
    {   // prefetch w1 (k=u*16, stride 4) and w2 (k=u*32, stride 8) lines
        float pf = 0.f;
        #pragma unroll
        for (int kk = 0; kk < 16; kk += 4)
            pf += w1[(size_t)(u * 16 + kk) * 256 + q * 4];
        #pragma unroll
        for (int kk = 0; kk < 32; kk += 8)
            pf += w2[(size_t)(u * 32 + kk) * 256 + q * 4];
        KEEP(pf);
    }
    warm(wa, na, gtid);
    if (t < 128) {
        float4 g4 = *(const float4*)&H[(size_t)r0 * 128 + t * 4];
        *(float4*)&hraw[t * 4] = g4;
    }
    if (t < 4) hmv[t] = hm[r0 + t];
    __syncthreads();
    // L1: K=128, thread covers k in [u*16, u*16+16), fully unrolled
    float acc[16];
    #pragma unroll
    for (int i = 0; i < 16; ++i) acc[i] = 0.f;
    #pragma unroll
    for (int kk = 0; kk < 16; ++kk) {
        int k = u * 16 + kk;
        float4 w4 = *(const float4*)&w1[(size_t)k * 256 + q * 4];
        float wc[4] = {w4.x, w4.y, w4.z, w4.w};
        float hr[4];
        #pragma unroll
        for (int r = 0; r < 4; ++r) hr[r] = hraw[r * 128 + k];
        #pragma unroll
        for (int r = 0; r < 4; ++r)
            #pragma unroll
            for (int c = 0; c < 4; ++c)
                acc[r * 4 + c] = fmaf(hr[r], wc[c], acc[r * 4 + c]);
    }
    #pragma unroll
    for (int r = 0; r < 4; ++r)
        *(float4*)&part[u * 1024 + r * 256 + q * 4] =
            make_float4(acc[r*4+0], acc[r*4+1], acc[r*4+2], acc[r*4+3]);
    __syncthreads();
    {   // combine L1 -> ph2 (relu): 1024 outputs, 2 per thread
        #pragma unroll
        for (int e = 0; e < 2; ++e) {
            int idx = e * 512 + t;
            int r = idx >> 8, f = idx & 255;
            float s = b1[f];
            #pragma unroll
            for (int uu = 0; uu < 8; ++uu) s += part[uu * 1024 + r * 256 + f];
            ph2[r * 256 + f] = fmaxf(s, 0.f);
        }
    }
    __syncthreads();
    // L2: K=256, thread covers k in [u*32, u*32+32), 16-deep unroll
    float a2[16];
    #pragma unroll
    for (int i = 0; i < 16; ++i) a2[i] = 0.f;
    #pragma unroll 16
    for (int kk = 0; kk < 32; ++kk) {
        int k = u * 32 + kk;
        float4 w4 = *(const float4*)&w2[(size_t)k * 256 + q * 4];
        float wc[4] = {w4.x, w4.y, w4.z, w4.w};
        float pv[4];
        #pragma unroll
        for (int r = 0; r < 4; ++r) pv[r] = ph2[r * 256 + k];
        #pragma unroll
        for (int r = 0; r < 4; ++r)
            #pragma unroll
            for (int c = 0; c < 4; ++c)
                a2[r * 4 + c] = fmaf(pv[r], wc[c], a2[r * 4 + c]);
    }
    __syncthreads();
    #pragma unroll
    for (int r = 0; r < 4; ++r)
        *(float4*)&part[u * 1024 + r * 256 + q * 4] =
            make_float4(a2[r*4+0], a2[r*4+1], a2[r*4+2], a2[r*4+3]);
    __syncthreads();
    if (t < 256) {   // final combine + relu + masked pool (f = t)
        float bb = b2[t];
        float hp = 0.f, sp = 0.f;
        #pragma unroll
        for (int r = 0; r < 4; ++r) {
            float s = bb;
            #pragma unroll
            for (int uu = 0; uu < 8; ++uu) s += part[uu * 1024 + r * 256 + t];
            float p = fmaxf(s, 0.f);
            sp += p;
            hp = fmaf(p, hmv[r], hp);
        }
        atomicAdd(&hsum[b * 256 + t], hp);
        atomicAdd(&asum[b * 256 + t], sp - hp);
    }
}

// ---------------------------------------------------------------------------
// k_rho: out[b] = 0.5 + 0.5*tanh(rho(home)-rho(away)); b2 cancels.
// ---------------------------------------------------------------------------
__global__ __launch_bounds__(256) void k_rho(const float* __restrict__ hsum,
        const float* __restrict__ asum,
        const float* __restrict__ w1, const float* __restrict__ b1,
        const float* __restrict__ w2, const float* __restrict__ b2,
        float* __restrict__ out) {
    const int bIdx = blockIdx.x;
    const int t = threadIdx.x, q = t & 31, u = t >> 5;
    __shared__ __align__(16) float part[2048];
    __shared__ __align__(16) float sv[512];
    __shared__ float wsv[2];
    sv[t] = hsum[bIdx * 256 + t];
    sv[256 + t] = asum[bIdx * 256 + t];
    __syncthreads();
    float aH[4] = {0.f, 0.f, 0.f, 0.f}, aA[4] = {0.f, 0.f, 0.f, 0.f};
    #pragma unroll 16
    for (int kk = 0; kk < 32; ++kk) {
        int k = u * 32 + kk;
        float4 w4 = *(const float4*)&w1[(size_t)k * 128 + q * 4];
        float sh = sv[k], sa = sv[256 + k];
        aH[0] = fmaf(sh, w4.x, aH[0]); aA[0] = fmaf(sa, w4.x, aA[0]);
        aH[1] = fmaf(sh, w4.y, aH[1]); aA[1] = fmaf(sa, w4.y, aA[1]);
        aH[2] = fmaf(sh, w4.z, aH[2]); aA[2] = fmaf(sa, w4.z, aA[2]);
        aH[3] = fmaf(sh, w4.w, aH[3]); aA[3] = fmaf(sa, w4.w, aA[3]);
    }
    *(float4*)&part[u * 256 + q * 4]       = make_float4(aH[0], aH[1], aH[2], aH[3]);
    *(float4*)&part[u * 256 + 128 + q * 4] = make_float4(aA[0], aA[1], aA[2], aA[3]);
    __syncthreads();
    if (t < 64) {
        int vec = t >> 5, fq = t & 31;
        float4 s = make_float4(0.f, 0.f, 0.f, 0.f);
        #pragma unroll
        for (int uu = 0; uu < 8; ++uu) {
            float4 p = *(const float4*)&part[uu * 256 + vec * 128 + fq * 4];
            s.x += p.x; s.y += p.y; s.z += p.z; s.w += p.w;
        }
        float4 bb = *(const float4*)&b1[fq * 4];
        float4 w2q = *(const float4*)&w2[fq * 4];
        float p = fmaxf(s.x + bb.x, 0.f) * w2q.x
                + fmaxf(s.y + bb.y, 0.f) * w2q.y
                + fmaxf(s.z + bb.z, 0.f) * w2q.z
                + fmaxf(s.w + bb.w, 0.f) * w2q.w;
        #pragma unroll
        for (int o = 16; o > 0; o >>= 1) p += __shfl_down(p, o, 32);
        if ((t & 31) == 0) wsv[vec] = p;
    }
    __syncthreads();
    if (t == 0) out[bIdx] = 0.5f + 0.5f * tanhf(wsv[0] - wsv[1]);
}

// ---------------------------------------------------------------------------
extern "C" void kernel_launch(void* const* d_in, const int* in_sizes, int n_in,
                              void* d_out, int out_size, void* d_ws, size_t ws_size,
                              hipStream_t stream) {
    const float* A         = (const float*)d_in[0];
    const float* X         = (const float*)d_in[1];
    const float* home_mask = (const float*)d_in[2];
    const float* emb1_w    = (const float*)d_in[3];
    const float* emb1_b    = (const float*)d_in[4];
    const float* emb2_w    = (const float*)d_in[5];
    const float* emb2_b    = (const float*)d_in[6];
    const float* rgcn_w[2]    = { (const float*)d_in[7],  (const float*)d_in[14] };
    const float* rgcn_root[2] = { (const float*)d_in[8],  (const float*)d_in[15] };
    const float* rgcn_bias[2] = { (const float*)d_in[9],  (const float*)d_in[16] };
    const float* lina_w[2]    = { (const float*)d_in[10], (const float*)d_in[17] };
    const float* lina_b[2]    = { (const float*)d_in[11], (const float*)d_in[18] };
    const float* linb_w[2]    = { (const float*)d_in[12], (const float*)d_in[19] };
    const float* linb_b[2]    = { (const float*)d_in[13], (const float*)d_in[20] };
    const float* norm_g  = (const float*)d_in[21];
    const float* norm_b  = (const float*)d_in[22];
    const float* phi_w1  = (const float*)d_in[23];
    const float* phi_b1  = (const float*)d_in[24];
    const float* phi_w2  = (const float*)d_in[25];
    const float* phi_b2  = (const float*)d_in[26];
    const float* rho_w1  = (const float*)d_in[27];
    const float* rho_b1  = (const float*)d_in[28];
    const float* rho_w2  = (const float*)d_in[29];
    const float* rho_b2  = (const float*)d_in[30];
    float* out = (float*)d_out;

    float* ws   = (float*)d_ws;
    float* H    = ws;               // 262144
    float* H2   = ws + 262144;      // 262144
    float* hsum = ws + 524288;      // 2048
    float* asum = ws + 526336;      // 2048 (contiguous with hsum)

    // Chain-warming: each kernel pulls the NEXT kernel's weights into L2/L3.
    k_embed<<<512, 512, 0, stream>>>(X, emb1_w, emb1_b, emb2_w, emb2_b, H, hsum,
                                     rgcn_w[0], 32768, rgcn_root[0], 16384);

    for (int it = 0; it < 2; ++it) {
        k_gcn1<<<512, 512, 0, stream>>>(A, H, rgcn_w[it], rgcn_root[it],
                                        rgcn_bias[it], H2,
                                        lina_w[it], 16384, linb_w[it], 16384);
        if (it == 0) {
            k_gcn2<<<512, 512, 0, stream>>>(A, H2, norm_g, norm_b,
                                            lina_w[0], lina_b[0],
                                            linb_w[0], linb_b[0], H,
                                            rgcn_w[1], 32768, rgcn_root[1], 16384);
        } else {
            k_gcn2<<<512, 512, 0, stream>>>(A, H2, norm_g, norm_b,
                                            lina_w[1], lina_b[1],
                                            linb_w[1], linb_b[1], H,
                                            phi_w1, 32768, phi_w2, 65536);
        }
    }

    k_deepset<<<512, 512, 0, stream>>>(H, home_mask, phi_w1, phi_b1,
                                       phi_w2, phi_b2, hsum, asum,
                                       rho_w1, 32768);
    k_rho<<<NB, 256, 0, stream>>>(hsum, asum, rho_w1, rho_b1, rho_w2, rho_b2, out);
}